// Round 15
// baseline (29.485 us; speedup 1.0000x reference)
//
#include <hip/hip_runtime.h>
#include <hip/hip_bf16.h>

// Grid_INR2D round 15: round-7 2-batch-ILP body at a GENEROUS register cap.
//  The {parallelism x reg-budget} matrix has one untested cell: 2-stream ILP
//  with __launch_bounds__(256,2) (cap 256 VGPR, 2 waves/SIMD). Round 7 ran
//  this body at cap 128 and collapsed (VGPR 64 + spill) -- theory untested.
//  Effective streams/SIMD = 2 waves x 2 streams = 4 = round 6's 4x1, but
//  with per-batch LDS frag reads halved (shared by both streams) and halved
//  issue contention per SIMD. Single-variable vs r7 (cap), interpretable vs
//  r6 (ILP vs TLP at equal stream count).
//  GATES: VGPR in [160,256] & WRITE=6144KB (collapse impossible-by-design);
//  dur>=29us -> wave-TLP wins, revert to round-14 source as final.
// Fragment identity (validated rounds 3-14):
//   A: row=lane&15, k=4*(lane>>4)+(e&3)+16*(e>>2); B: col=lane&15, same k;
//   C/D: col=lane&15, row=4*(lane>>4)+reg  ==> C-frag of layer n is B-frag
//   of layer n+1 per-lane: B[kb].e = bf16(relu(C[2kb+(e>=4)].reg[e&3])).

typedef float f32x4 __attribute__((ext_vector_type(4)));
typedef short s16x8 __attribute__((ext_vector_type(8)));

#define MFMA16(a, b, c) __builtin_amdgcn_mfma_f32_16x16x32_bf16((a), (b), (c), 0, 0, 0)

__device__ __forceinline__ short bfbits(float f) {   // RNE via HW cvt
    return __builtin_bit_cast(short, __float2bfloat16(f));
}

__device__ __forceinline__ s16x8 pack_relu(const f32x4 lo, const f32x4 hi) {
    s16x8 r;
#pragma unroll
    for (int e = 0; e < 4; ++e) {
        r[e]     = bfbits(fmaxf(lo[e], 0.0f));
        r[e + 4] = bfbits(fmaxf(hi[e], 0.0f));
    }
    return r;
}

// LDS frag table: fid 0..11 = w1[mt*3+kb], 12..19 = w2[mt*2+kb], 20..21 = w3[kb]
#define NFRAG 22

__global__ __launch_bounds__(256, 2) void grid_inr_mfma(
    const float* __restrict__ feat,
    const float* __restrict__ g0, const float* __restrict__ g1,
    const float* __restrict__ g2, const float* __restrict__ g3,
    const float* __restrict__ w1, const float* __restrict__ b1,
    const float* __restrict__ w2, const float* __restrict__ b2,
    const float* __restrict__ w3, const float* __restrict__ b3,
    float* __restrict__ out)
{
    __shared__ __align__(16) short lds_w[NFRAG * 64 * 8];
    __shared__ __align__(16) float lds_b2[64];

    const int lane  = threadIdx.x & 63;
    const int col   = lane & 15;    // A row / B col / pixel-in-tile
    const int lrow  = lane >> 4;    // k-group
    const int wv    = threadIdx.x >> 6;
    const int p     = blockIdx.x * 64 + wv * 16 + col;   // this lane's pixel

    // ---------------- stage weight A-frags + b2 into LDS (once per block) ---
    if (threadIdx.x < 64) lds_b2[threadIdx.x] = b2[threadIdx.x];
    {
        const int cs = lane, c15 = lane & 15, r4 = lane >> 4;
#pragma unroll 1
        for (int fid = threadIdx.x >> 6; fid < NFRAG; fid += 4) {
            const float* src;
            if (fid < 12) {
                const int mt = fid / 3, kb = fid - 3 * mt;
                src = w1 + (16 * mt + c15) * 96 + 32 * kb + 4 * r4;
            } else if (fid < 20) {
                const int f = fid - 12, mt = f >> 1, kb = f & 1;
                src = w2 + (16 * mt + c15) * 64 + 32 * kb + 4 * r4;
            } else {
                const int kb = fid - 20;
                const int row3 = (c15 < 3) ? c15 : 2;   // junk rows unused
                src = w3 + row3 * 64 + 32 * kb + 4 * r4;
            }
            s16x8 frag;
#pragma unroll
            for (int e = 0; e < 8; ++e)
                frag[e] = bfbits(src[(e & 3) + 16 * (e >> 2)]);
            *(s16x8*)&lds_w[(fid * 64 + cs) * 8] = frag;
        }
    }

    const float b3s0 = b3[0], b3s1 = b3[1], b3s2 = b3[2];  // uniform s_loads

    // ---------------- grid-sample -> localB[2] (B-frags, k=local ch) --------
    s16x8 localB[2];
    {
        const float* gs[4] = {g0, g1, g2, g3};
        const int    gn[4] = {32, 64, 128, 256};
        const int px = p & 255;
        const int py = p >> 8;
#pragma unroll
        for (int lv = 0; lv < 4; ++lv) {
            const int G = gn[lv];
            const float ix = (float)((2 * px + 1) * (G - 1)) * (1.0f / 512.0f);
            const float iy = (float)((2 * py + 1) * (G - 1)) * (1.0f / 512.0f);
            int ix0 = (int)ix;
            int iy0 = (int)iy;
            if (ix0 > G - 1) ix0 = G - 1;
            if (iy0 > G - 1) iy0 = G - 1;
            const int ix1 = (ix0 + 1 < G - 1) ? (ix0 + 1) : (G - 1);
            const int iy1 = (iy0 + 1 < G - 1) ? (iy0 + 1) : (G - 1);
            const float wx = ix - (float)ix0;
            const float wy = iy - (float)iy0;
            const float w00 = (1.0f - wy) * (1.0f - wx);
            const float w01 = (1.0f - wy) * wx;
            const float w10 = wy * (1.0f - wx);
            const float w11 = wy * wx;
            const int o00 = iy0 * G + ix0;
            const int o01 = iy0 * G + ix1;
            const int o10 = iy1 * G + ix0;
            const int o11 = iy1 * G + ix1;
            const float* g = gs[lv];
            const int GG = G * G;
#pragma unroll
            for (int j = 0; j < 4; ++j) {
                const float* gc = g + (4 * lrow + j) * GG;
                const float v = gc[o00] * w00 + gc[o01] * w01 +
                                gc[o10] * w10 + gc[o11] * w11;
                localB[lv >> 1][(lv & 1) * 4 + j] = bfbits(v);
            }
        }
    }

    __syncthreads();   // LDS frag table ready

    const short* lw = lds_w + lane * 8;      // per-lane base; fid via offset
#define LDSFRAG(fid) (*(const s16x8*)(lw + (fid) * 64 * 8))

    // ---- reg-cache w1-feat frags; hoist batch-invariant layer-1 base -------
    s16x8 w1ff[4];
#pragma unroll
    for (int mt = 0; mt < 4; ++mt) w1ff[mt] = LDSFRAG(mt * 3);

    f32x4 c1base[4];
#pragma unroll
    for (int mt = 0; mt < 4; ++mt) {
        c1base[mt] = *(const f32x4*)(b1 + 16 * mt + 4 * lrow);
        c1base[mt] = MFMA16(LDSFRAG(mt * 3 + 1), localB[0], c1base[mt]);
        c1base[mt] = MFMA16(LDSFRAG(mt * 3 + 2), localB[1], c1base[mt]);
    }
    // localB dead from here.

    // ---- batch-pair loop: A=2bp, B=2bp+1 fully interleaved -----------------
    float rawP[8], rawQ[8];
#pragma unroll
    for (int e = 0; e < 8; ++e) {
        const int fc = 4 * lrow + (e & 3) + 16 * (e >> 2);
        rawP[e] = feat[(fc << 16) + p];          // batch 0
        rawQ[e] = feat[((32 + fc) << 16) + p];   // batch 1
    }

#pragma unroll 1
    for (int bp = 0; bp < 4; ++bp) {
        s16x8 ffA, ffB;
#pragma unroll
        for (int e = 0; e < 8; ++e) ffA[e] = bfbits(rawP[e]);
#pragma unroll
        for (int e = 0; e < 8; ++e) ffB[e] = bfbits(rawQ[e]);
        if (bp < 3) {   // issue both next-pair load sets together (16 in flight)
#pragma unroll
            for (int e = 0; e < 8; ++e) {
                const int fc = 4 * lrow + (e & 3) + 16 * (e >> 2);
                rawP[e] = feat[((((2 * bp + 2) << 5) | fc) << 16) + p];
                rawQ[e] = feat[((((2 * bp + 3) << 5) | fc) << 16) + p];
            }
        }

        // layer 1: two independent streams off the shared w1ff/c1base
        f32x4 c1A[4], c1B[4];
#pragma unroll
        for (int mt = 0; mt < 4; ++mt) {
            c1A[mt] = MFMA16(w1ff[mt], ffA, c1base[mt]);
            c1B[mt] = MFMA16(w1ff[mt], ffB, c1base[mt]);
        }
        s16x8 h1A0 = pack_relu(c1A[0], c1A[1]);
        s16x8 h1A1 = pack_relu(c1A[2], c1A[3]);
        s16x8 h1B0 = pack_relu(c1B[0], c1B[1]);
        s16x8 h1B1 = pack_relu(c1B[2], c1B[3]);

        // layer 2: w2/b2 frags read once, feed both streams
        f32x4 c2A[4], c2B[4];
#pragma unroll
        for (int mt = 0; mt < 4; ++mt) {
            const f32x4 bb = *(const f32x4*)&lds_b2[16 * mt + 4 * lrow];
            const s16x8 wk0 = LDSFRAG(12 + 2 * mt);
            const s16x8 wk1 = LDSFRAG(12 + 2 * mt + 1);
            c2A[mt] = MFMA16(wk1, h1A1, MFMA16(wk0, h1A0, bb));
            c2B[mt] = MFMA16(wk1, h1B1, MFMA16(wk0, h1B0, bb));
        }
        s16x8 h2A0 = pack_relu(c2A[0], c2A[1]);
        s16x8 h2A1 = pack_relu(c2A[2], c2A[3]);
        s16x8 h2B0 = pack_relu(c2B[0], c2B[1]);
        s16x8 h2B1 = pack_relu(c2B[2], c2B[3]);

        // layer 3: w3 frags read once, feed both streams
        const s16x8 w30 = LDSFRAG(20);
        const s16x8 w31 = LDSFRAG(21);
        const f32x4 z = {0.f, 0.f, 0.f, 0.f};
        const f32x4 c3A = MFMA16(w31, h2A1, MFMA16(w30, h2A0, z));
        const f32x4 c3B = MFMA16(w31, h2B1, MFMA16(w30, h2B0, z));

        if (lrow == 0) {
            const int bA = 2 * bp, bB = 2 * bp + 1;
            out[((bA * 3 + 0) << 16) + p] = c3A[0] + b3s0;
            out[((bA * 3 + 1) << 16) + p] = c3A[1] + b3s1;
            out[((bA * 3 + 2) << 16) + p] = c3A[2] + b3s2;
            out[((bB * 3 + 0) << 16) + p] = c3B[0] + b3s0;
            out[((bB * 3 + 1) << 16) + p] = c3B[1] + b3s1;
            out[((bB * 3 + 2) << 16) + p] = c3B[2] + b3s2;
        }
    }
#undef LDSFRAG
}

extern "C" void kernel_launch(void* const* d_in, const int* in_sizes, int n_in,
                              void* d_out, int out_size, void* d_ws, size_t ws_size,
                              hipStream_t stream) {
    const float* feat = (const float*)d_in[0];
    const float* g0   = (const float*)d_in[1];
    const float* g1   = (const float*)d_in[2];
    const float* g2   = (const float*)d_in[3];
    const float* g3   = (const float*)d_in[4];
    const float* w1   = (const float*)d_in[5];
    const float* b1   = (const float*)d_in[6];
    const float* w2   = (const float*)d_in[7];
    const float* b2   = (const float*)d_in[8];
    const float* w3   = (const float*)d_in[9];
    const float* b3   = (const float*)d_in[10];

    // 65536 px / (16 px/wave * 4 waves) = 1024 blocks; all 8 batches inside.
    // At (256,2): 512 blocks resident (2/CU), 512 queued.
    grid_inr_mfma<<<1024, 256, 0, stream>>>(
        feat, g0, g1, g2, g3, w1, b1, w2, b2, w3, b3, (float*)d_out);
}

// Round 16
// 28.801 us; speedup vs baseline: 1.0238x; 1.0238x over previous
//
#include <hip/hip_runtime.h>
#include <hip/hip_bf16.h>

// Grid_INR2D round 16: round-14 structure + COALESCED weight staging.
//  r15 evidence: 2-stream body fit in 76 VGPR (zero spill) and ~8 effective
//  streams/SIMD did NOT beat round 6 -> the batch loop is not the limiter.
//  Pipe accounting of the 28.8us: staging does 8 scalar f32 loads per frag
//  per lane; each wave-load spans 16 rows (384B apart) = ~16 cachelines ->
//  176 instrs x 16 CL x 1024 blocks ~= 2.9M L2 transactions (~184MB traffic
//  for 45KB of weights). Fix: one f32x4 load of 4 CONSECUTIVE weights per
//  thread-unit (u -> fid,h,r4,c15), cvt to 4 bf16, 8B ds_write at
//  lane-stride-16B (2-way bank alias = free). 4x fewer transactions,
//  44->11 load instrs/wave. Same elements, same RNE, same LDS layout ->
//  frag table bit-identical; batch loop byte-identical to round 14.
//  GATES: absmax exactly 0.0078125; WRITE_SIZE 6144KB; VGPR ~100-128.
// Fragment identity (validated rounds 3-15):
//   A: row=lane&15, k=4*(lane>>4)+(e&3)+16*(e>>2); B: col=lane&15, same k;
//   C/D: col=lane&15, row=4*(lane>>4)+reg  ==> C-frag of layer n is B-frag
//   of layer n+1 per-lane: B[kb].e = bf16(relu(C[2kb+(e>=4)].reg[e&3])).

typedef float f32x4 __attribute__((ext_vector_type(4)));
typedef short s16x4 __attribute__((ext_vector_type(4)));
typedef short s16x8 __attribute__((ext_vector_type(8)));

#define MFMA16(a, b, c) __builtin_amdgcn_mfma_f32_16x16x32_bf16((a), (b), (c), 0, 0, 0)

__device__ __forceinline__ short bfbits(float f) {   // RNE via HW cvt
    return __builtin_bit_cast(short, __float2bfloat16(f));
}

__device__ __forceinline__ s16x8 pack_relu(const f32x4 lo, const f32x4 hi) {
    s16x8 r;
#pragma unroll
    for (int e = 0; e < 4; ++e) {
        r[e]     = bfbits(fmaxf(lo[e], 0.0f));
        r[e + 4] = bfbits(fmaxf(hi[e], 0.0f));
    }
    return r;
}

// LDS frag table: fid 0..11 = w1[mt*3+kb], 12..19 = w2[mt*2+kb], 20..21 = w3[kb]
#define NFRAG 22

__global__ __launch_bounds__(256, 4) void grid_inr_mfma(
    const float* __restrict__ feat,
    const float* __restrict__ g0, const float* __restrict__ g1,
    const float* __restrict__ g2, const float* __restrict__ g3,
    const float* __restrict__ w1, const float* __restrict__ b1,
    const float* __restrict__ w2, const float* __restrict__ b2,
    const float* __restrict__ w3, const float* __restrict__ b3,
    float* __restrict__ out)
{
    __shared__ __align__(16) short lds_w[NFRAG * 64 * 8];

    const int lane  = threadIdx.x & 63;
    const int col   = lane & 15;    // A row / B col / pixel-in-tile
    const int lrow  = lane >> 4;    // k-group
    const int wv    = threadIdx.x >> 6;
    const int p     = blockIdx.x * 64 + wv * 16 + col;   // this lane's pixel

    // -------- stage weight A-frags into LDS: COALESCED (once per block) ----
    // unit u: fid = u>>7; v = u&127; h = v>>6; r4 = (v>>4)&3; c15 = v&15.
    // Each unit: f32x4 load of 4 consecutive weights (cols 32kb+4r4+16h ..+3)
    // -> 4 bf16 -> 8B ds_write at frag slot (fid*64 + c15+16r4)*8 + 4h.
    // Wave iteration: 16 rows x 1 CL = 16 CLs for 1KB useful (vs ~16 CL per
    // SINGLE scalar load before). LDS write stride 16B/lane: conflict-free.
#pragma unroll 1
    for (int u = threadIdx.x; u < NFRAG * 128; u += 256) {
        const int fid = u >> 7;
        const int v   = u & 127;
        const int h   = v >> 6;
        const int r4  = (v >> 4) & 3;
        const int c15 = v & 15;
        const float* src;
        if (fid < 12) {
            const int mt = fid / 3, kb = fid - 3 * mt;
            src = w1 + (16 * mt + c15) * 96 + 32 * kb + 4 * r4 + 16 * h;
        } else if (fid < 20) {
            const int f = fid - 12, mt = f >> 1, kb = f & 1;
            src = w2 + (16 * mt + c15) * 64 + 32 * kb + 4 * r4 + 16 * h;
        } else {
            const int kb = fid - 20;
            const int row3 = (c15 < 3) ? c15 : 2;   // junk rows unused
            src = w3 + row3 * 64 + 32 * kb + 4 * r4 + 16 * h;
        }
        const f32x4 wq = *(const f32x4*)src;
        s16x4 pk;
#pragma unroll
        for (int j = 0; j < 4; ++j) pk[j] = bfbits(wq[j]);
        *(s16x4*)&lds_w[(fid * 64 + c15 + 16 * r4) * 8 + 4 * h] = pk;
    }

    // ---------------- biases in regs (f32, per-lane rows) -------------------
    f32x4 b1f[4], b2f[4];
#pragma unroll
    for (int mt = 0; mt < 4; ++mt) {
        b1f[mt] = *(const f32x4*)(b1 + 16 * mt + 4 * lrow);
        b2f[mt] = *(const f32x4*)(b2 + 16 * mt + 4 * lrow);
    }
    const float b3s0 = b3[0], b3s1 = b3[1], b3s2 = b3[2];  // uniform s_loads

    // ---------------- grid-sample -> localB[2] (B-frags, k=local ch) --------
    s16x8 localB[2];
    {
        const float* gs[4] = {g0, g1, g2, g3};
        const int    gn[4] = {32, 64, 128, 256};
        const int px = p & 255;
        const int py = p >> 8;
#pragma unroll
        for (int lv = 0; lv < 4; ++lv) {
            const int G = gn[lv];
            const float ix = (float)((2 * px + 1) * (G - 1)) * (1.0f / 512.0f);
            const float iy = (float)((2 * py + 1) * (G - 1)) * (1.0f / 512.0f);
            int ix0 = (int)ix;
            int iy0 = (int)iy;
            if (ix0 > G - 1) ix0 = G - 1;
            if (iy0 > G - 1) iy0 = G - 1;
            const int ix1 = (ix0 + 1 < G - 1) ? (ix0 + 1) : (G - 1);
            const int iy1 = (iy0 + 1 < G - 1) ? (iy0 + 1) : (G - 1);
            const float wx = ix - (float)ix0;
            const float wy = iy - (float)iy0;
            const float w00 = (1.0f - wy) * (1.0f - wx);
            const float w01 = (1.0f - wy) * wx;
            const float w10 = wy * (1.0f - wx);
            const float w11 = wy * wx;
            const int o00 = iy0 * G + ix0;
            const int o01 = iy0 * G + ix1;
            const int o10 = iy1 * G + ix0;
            const int o11 = iy1 * G + ix1;
            const float* g = gs[lv];
            const int GG = G * G;
#pragma unroll
            for (int j = 0; j < 4; ++j) {
                const float* gc = g + (4 * lrow + j) * GG;
                const float v = gc[o00] * w00 + gc[o01] * w01 +
                                gc[o10] * w10 + gc[o11] * w11;
                localB[lv >> 1][(lv & 1) * 4 + j] = bfbits(v);
            }
        }
    }

    __syncthreads();   // LDS frag table ready

    const short* lw = lds_w + lane * 8;      // per-lane base; fid via offset
#define LDSFRAG(fid) (*(const s16x8*)(lw + (fid) * 64 * 8))

    // ---- register-cache small frag groups; hoist batch-invariant layer-1 ---
    s16x8 w1ff[4], w3f[2];
#pragma unroll
    for (int mt = 0; mt < 4; ++mt) w1ff[mt] = LDSFRAG(mt * 3);
    w3f[0] = LDSFRAG(20);
    w3f[1] = LDSFRAG(21);

    // c1base[mt] = b1 + W1[:,32:96] . local   (batch-invariant, once)
    f32x4 c1base[4];
#pragma unroll
    for (int mt = 0; mt < 4; ++mt) {
        c1base[mt] = b1f[mt];
        c1base[mt] = MFMA16(LDSFRAG(mt * 3 + 1), localB[0], c1base[mt]);
        c1base[mt] = MFMA16(LDSFRAG(mt * 3 + 2), localB[1], c1base[mt]);
    }

    // ---- per-batch MLP body (b only feeds store addressing) ----------------
    auto process = [&](int b, const s16x8 ff) {
        f32x4 c1[4];
#pragma unroll
        for (int mt = 0; mt < 4; ++mt)
            c1[mt] = MFMA16(w1ff[mt], ff, c1base[mt]);

        s16x8 h1b0 = pack_relu(c1[0], c1[1]);
        s16x8 h1b1 = pack_relu(c1[2], c1[3]);

        f32x4 c2[4];
#pragma unroll
        for (int mt = 0; mt < 4; ++mt) {
            c2[mt] = b2f[mt];
            c2[mt] = MFMA16(LDSFRAG(12 + mt * 2),     h1b0, c2[mt]);
            c2[mt] = MFMA16(LDSFRAG(12 + mt * 2 + 1), h1b1, c2[mt]);
        }
        s16x8 h2b0 = pack_relu(c2[0], c2[1]);
        s16x8 h2b1 = pack_relu(c2[2], c2[3]);

        f32x4 c3 = {0.f, 0.f, 0.f, 0.f};
        c3 = MFMA16(w3f[0], h2b0, c3);
        c3 = MFMA16(w3f[1], h2b1, c3);

        if (lrow == 0) {
            out[((b * 3 + 0) << 16) + p] = c3[0] + b3s0;
            out[((b * 3 + 1) << 16) + p] = c3[1] + b3s1;
            out[((b * 3 + 2) << 16) + p] = c3[2] + b3s2;
        }
    };

    // ---- batch loop: 2-deep feat prefetch via named ping-pong buffers ------
    float rawP[8], rawQ[8];
#pragma unroll
    for (int e = 0; e < 8; ++e) {
        const int fc = 4 * lrow + (e & 3) + 16 * (e >> 2);
        rawP[e] = feat[(fc << 16) + p];          // batch 0
        rawQ[e] = feat[((32 + fc) << 16) + p];   // batch 1
    }

#pragma unroll 1
    for (int bp = 0; bp < 4; ++bp) {
        // batch A = 2*bp (from rawP); refill rawP with batch 2*bp+2
        s16x8 ff;
#pragma unroll
        for (int e = 0; e < 8; ++e) ff[e] = bfbits(rawP[e]);
        if (bp < 3) {
#pragma unroll
            for (int e = 0; e < 8; ++e) {
                const int fc = 4 * lrow + (e & 3) + 16 * (e >> 2);
                rawP[e] = feat[((((2 * bp + 2) << 5) | fc) << 16) + p];
            }
        }
        process(2 * bp, ff);

        // batch B = 2*bp+1 (from rawQ); refill rawQ with batch 2*bp+3
#pragma unroll
        for (int e = 0; e < 8; ++e) ff[e] = bfbits(rawQ[e]);
        if (bp < 3) {
#pragma unroll
            for (int e = 0; e < 8; ++e) {
                const int fc = 4 * lrow + (e & 3) + 16 * (e >> 2);
                rawQ[e] = feat[((((2 * bp + 3) << 5) | fc) << 16) + p];
            }
        }
        process(2 * bp + 1, ff);
    }
#undef LDSFRAG
}

extern "C" void kernel_launch(void* const* d_in, const int* in_sizes, int n_in,
                              void* d_out, int out_size, void* d_ws, size_t ws_size,
                              hipStream_t stream) {
    const float* feat = (const float*)d_in[0];
    const float* g0   = (const float*)d_in[1];
    const float* g1   = (const float*)d_in[2];
    const float* g2   = (const float*)d_in[3];
    const float* g3   = (const float*)d_in[4];
    const float* w1   = (const float*)d_in[5];
    const float* b1   = (const float*)d_in[6];
    const float* w2   = (const float*)d_in[7];
    const float* b2   = (const float*)d_in[8];
    const float* w3   = (const float*)d_in[9];
    const float* b3   = (const float*)d_in[10];

    // 65536 px / (16 px/wave * 4 waves) = 1024 blocks; all 8 batches inside.
    grid_inr_mfma<<<1024, 256, 0, stream>>>(
        feat, g0, g1, g2, g3, w1, b1, w2, b2, w3, b3, (float*)d_out);
}